// Round 7
// baseline (212.843 us; speedup 1.0000x reference)
//
#include <hip/hip_runtime.h>
#include <math.h>

#define NTT 365
#define NSS 300
#define NROWS (NTT*NSS)   // 109500
#define TPAD 384          // padded time steps for branchless prefetch

using bf16x8 = __attribute__((ext_vector_type(8))) short;
using f32x4  = __attribute__((ext_vector_type(4))) float;

__device__ __forceinline__ float sigf(float v) { return 1.0f / (1.0f + __expf(-v)); }

__device__ __forceinline__ float tanhfast(float x) {
    float e = __expf(2.0f * x);
    return 1.0f - 2.0f * __builtin_amdgcn_rcpf(1.0f + e);
}

__device__ __forceinline__ unsigned short f2bf(float f) {
    unsigned u = __builtin_bit_cast(unsigned, f);
    u += 0x7FFFu + ((u >> 16) & 1u);
    return (unsigned short)(u >> 16);
}

// ---------------- K0: swizzle fcT weights to fragment-major bf16 ----------------
__global__ __launch_bounds__(256) void k_prep(const float* __restrict__ w1,
                                              const float* __restrict__ w2,
                                              unsigned short* __restrict__ w1s,
                                              unsigned short* __restrict__ w2s)
{
    int G = blockIdx.x * 256 + threadIdx.x;
    if (G < 2048) {
        int lane = G & 63, ks = (G >> 6) & 1, tile = G >> 7;
        int o = tile * 16 + (lane & 15);
        int kb = ks * 32 + (lane >> 4) * 8;
        unsigned short tmp[8];
#pragma unroll
        for (int e = 0; e < 8; ++e) {
            int k = kb + e;
            tmp[e] = (k < 38) ? f2bf(w1[o * 38 + k]) : (unsigned short)0;
        }
        *(bf16x8*)(w1s + (size_t)G * 8) = *(bf16x8*)tmp;
    } else if (G < 2048 + 12288) {
        int G2 = G - 2048;
        int lane = G2 & 63, ks = (G2 >> 6) & 7, tile = G2 >> 9;
        int o = tile * 16 + (lane & 15);
        int kb = ks * 32 + (lane >> 4) * 8;
        unsigned short tmp[8];
#pragma unroll
        for (int e = 0; e < 8; ++e) tmp[e] = f2bf(w2[o * 256 + kb + e]);
        *(bf16x8*)(w2s + (size_t)G2 * 8) = *(bf16x8*)tmp;
    }
}

// ---------------- K1: per-site MLPs, output-sliced grid (30 x 8) ----------------
__global__ __launch_bounds__(256) void k_site(
    const float* __restrict__ xc,
    const float* __restrict__ wW1, const float* __restrict__ bW1,
    const float* __restrict__ wW2, const float* __restrict__ bW2,
    const float* __restrict__ wR1, const float* __restrict__ bR1,
    const float* __restrict__ wR2, const float* __restrict__ bR2,
    float* __restrict__ wsite, float* __restrict__ rsite)
{
    __shared__ float xcb[10][32];
    __shared__ float hW[10][256];
    __shared__ float hR[10][256];
    int tid = threadIdx.x;
    int s0 = blockIdx.x * 10;
    int os = blockIdx.y;              // 0..7 output slice
    for (int i = tid; i < 10 * 32; i += 256) xcb[i / 32][i % 32] = xc[s0 * 32 + i];
    __syncthreads();
    {
        int j = tid;
        float aW[10], aR[10];
#pragma unroll
        for (int r = 0; r < 10; ++r) { aW[r] = bW1[j]; aR[r] = bR1[j]; }
        for (int k = 0; k < 32; ++k) {
            float wv = wW1[j * 32 + k], rv = wR1[j * 32 + k];
#pragma unroll
            for (int r = 0; r < 10; ++r) { float xv = xcb[r][k]; aW[r] += xv * wv; aR[r] += xv * rv; }
        }
#pragma unroll
        for (int r = 0; r < 10; ++r) { hW[r][j] = tanhfast(aW[r]); hR[r][j] = tanhfast(aR[r]); }
    }
    __syncthreads();
    if (tid < 240) {
        int o_lin = os * 240 + tid;   // 0..1919
        float acc[10];
        if (o_lin < 896) {
            int o = o_lin;
#pragma unroll
            for (int r = 0; r < 10; ++r) acc[r] = bW2[o];
            for (int k = 0; k < 256; ++k) {
                float wv = wW2[o * 256 + k];
#pragma unroll
                for (int r = 0; r < 10; ++r) acc[r] += hW[r][k] * wv;
            }
#pragma unroll
            for (int r = 0; r < 10; ++r) wsite[(s0 + r) * 896 + o] = acc[r];
        } else {
            int o = o_lin - 896;      // 0..1023
#pragma unroll
            for (int r = 0; r < 10; ++r) acc[r] = bR2[o];
            for (int k = 0; k < 256; ++k) {
                float wv = wR2[o * 256 + k];
#pragma unroll
                for (int r = 0; r < 10; ++r) acc[r] += hR[r][k] * wv;
            }
#pragma unroll
            for (int r = 0; r < 10; ++r) rsite[(s0 + r) * 1024 + o] = acc[r];
        }
    }
}

// ---------------- K1b: softmax of ga over h per site ----------------
__global__ __launch_bounds__(128) void k_softmax_ga(const float* __restrict__ wsite,
                                                    float* __restrict__ ga)
{
    int s = blockIdx.x, tid = threadIdx.x;
    __shared__ float red[2];
    float v = wsite[s * 896 + 6 * 128 + tid];
    float m = v;
#pragma unroll
    for (int off = 32; off >= 1; off >>= 1) m = fmaxf(m, __shfl_xor(m, off));
    if ((tid & 63) == 0) red[tid >> 6] = m;
    __syncthreads();
    m = fmaxf(red[0], red[1]);
    __syncthreads();
    float e = __expf(v - m);
    float ssum = e;
#pragma unroll
    for (int off = 32; off >= 1; off >>= 1) ssum += __shfl_xor(ssum, off);
    if ((tid & 63) == 0) red[tid >> 6] = ssum;
    __syncthreads();
    ssum = red[0] + red[1];
    ga[s * 128 + tid] = e / ssum;
}

// ---------------- K1c: precompute ct gate params per (s,h) ----------------
__global__ __launch_bounds__(128) void k_ct(const float* __restrict__ xc,
                                            const float* __restrict__ ctw,
                                            const float* __restrict__ ctb,
                                            float* __restrict__ ctp8,
                                            float* __restrict__ ctpb)
{
    __shared__ float xcs[32];
    int s = blockIdx.x, h = threadIdx.x;
    if (h < 32) xcs[h] = xc[s * 32 + h];
    __syncthreads();
    const float L2E = 1.4426950408889634f;
    const float LG01 = -3.3219280948873623f;   // log2(0.1): folds /10 into cp
    float out[8];
    float cgb = 0.0f;
#pragma unroll
    for (int g = 0; g < 3; ++g) {
        const float* wr = ctw + (g * 128 + h) * 34;
        float base = ctb[g * 128 + h];
        for (int k = 0; k < 32; ++k) base += wr[2 + k] * xcs[k];
        float w0 = wr[0] * L2E, w1 = wr[1] * L2E;
        float bb = base * L2E + ((g == 0) ? LG01 : 0.0f);
        if (g == 0) { out[0] = w0; out[1] = w1; out[2] = bb; }
        else if (g == 1) { out[3] = w0; out[4] = w1; out[5] = bb; }
        else { out[6] = w0; out[7] = w1; cgb = bb; }
    }
    float4* dst = (float4*)(ctp8 + ((size_t)s * 128 + h) * 8);
    dst[0] = make_float4(out[0], out[1], out[2], out[3]);
    dst[1] = make_float4(out[4], out[5], out[6], out[7]);
    ctpb[(size_t)s * 128 + h] = cgb;
}

// ---------------- K2: fcT MLP via bf16 MFMA -> PT, NVu{bf16 net, bf16 vm} ----------------
__global__ __launch_bounds__(512) void k_fcT(
    const float* __restrict__ x, const float* __restrict__ xc,
    const unsigned short* __restrict__ w1s, const float* __restrict__ b1,
    const unsigned short* __restrict__ w2s, const float* __restrict__ b2,
    float4* __restrict__ PT, unsigned* __restrict__ NVu)
{
    __shared__ unsigned short A1[64][72];
    __shared__ unsigned short hb[64][264];
    __shared__ float2 pfE[64];           // {P*(1-vf), 2*E}
    int tid = threadIdx.x;
    int row0 = blockIdx.x * 64;

    for (int idx = tid; idx < 64 * 64; idx += 512) {
        int r = idx >> 6, c = idx & 63;
        int g = row0 + r;
        float val = 0.0f;
        if (g < NROWS) {
            if (c < 6) val = x[g * 6 + c];
            else if (c < 38) { int s = g % NSS; val = xc[s * 32 + (c - 6)]; }
        }
        A1[r][c] = f2bf(val);
    }
    if (tid < 64) {
        int r = tid, g = row0 + r;
        float P = 0, E = 0, T1 = 0, T2 = 0;
        if (g < NROWS) { P = x[g * 6]; E = x[g * 6 + 1]; T1 = x[g * 6 + 2]; T2 = x[g * 6 + 3]; }
        float den = T2 - T1;
        float dg = (den == 0.0f) ? 1.0f : den;
        float ratio = fminf(fmaxf((T1 + T2) / dg, -1.0f), 1.0f);
        float vf = acosf(ratio) * (1.0f / 3.1415f);
        vf = (T1 >= 0.0f) ? 0.0f : ((T2 <= 0.0f) ? 1.0f : vf);
        pfE[r] = make_float2(P * (1.0f - vf), 2.0f * E);
        if (g < NROWS) PT[g] = make_float4(P * vf, T1, T2, vf);
    }
    __syncthreads();

    int lane = tid & 63, wv = tid >> 6;
    int r16 = lane & 15;
    int kg = (lane >> 4) * 8;     // k offset within 32-chunk
    int rq = (lane >> 4) * 4;     // row offset of C frag

    // ---- layer 1: [64 x 64(Kpad)] @ [256 x 64]^T -> hidden (bf16) ----
    {
        int mt = wv & 3, nb = (wv >> 2) * 8;
        f32x4 acc[8];
#pragma unroll
        for (int i = 0; i < 8; ++i) acc[i] = (f32x4){0.f, 0.f, 0.f, 0.f};
#pragma unroll
        for (int ks = 0; ks < 2; ++ks) {
            bf16x8 a = *(const bf16x8*)&A1[mt * 16 + r16][ks * 32 + kg];
#pragma unroll
            for (int i = 0; i < 8; ++i) {
                bf16x8 b = *(const bf16x8*)(w1s + ((size_t)(((nb + i) * 2 + ks) * 64 + lane) << 3));
                acc[i] = __builtin_amdgcn_mfma_f32_16x16x32_bf16(a, b, acc[i], 0, 0, 0);
            }
        }
#pragma unroll
        for (int i = 0; i < 8; ++i) {
            int col = (nb + i) * 16 + r16;
            float bias = b1[col];
#pragma unroll
            for (int j = 0; j < 4; ++j) {
                int row = mt * 16 + rq + j;
                hb[row][col] = f2bf(tanhfast(acc[i][j] + bias));
            }
        }
    }
    __syncthreads();

    // ---- layer 2: [64 x 256] @ [384 x 256]^T, wave w -> col tiles {w, w+8, w+16} ----
    {
        int t0 = wv, t1 = wv + 8, t2 = wv + 16;
        f32x4 acc[4][3];
#pragma unroll
        for (int m = 0; m < 4; ++m)
#pragma unroll
            for (int c = 0; c < 3; ++c) acc[m][c] = (f32x4){0.f, 0.f, 0.f, 0.f};
#pragma unroll
        for (int ks = 0; ks < 8; ++ks) {
            bf16x8 b0 = *(const bf16x8*)(w2s + ((size_t)((t0 * 8 + ks) * 64 + lane) << 3));
            bf16x8 b1v = *(const bf16x8*)(w2s + ((size_t)((t1 * 8 + ks) * 64 + lane) << 3));
            bf16x8 b2v = *(const bf16x8*)(w2s + ((size_t)((t2 * 8 + ks) * 64 + lane) << 3));
#pragma unroll
            for (int m = 0; m < 4; ++m) {
                bf16x8 a = *(const bf16x8*)&hb[m * 16 + r16][ks * 32 + kg];
                acc[m][0] = __builtin_amdgcn_mfma_f32_16x16x32_bf16(a, b0, acc[m][0], 0, 0, 0);
                acc[m][1] = __builtin_amdgcn_mfma_f32_16x16x32_bf16(a, b1v, acc[m][1], 0, 0, 0);
                acc[m][2] = __builtin_amdgcn_mfma_f32_16x16x32_bf16(a, b2v, acc[m][2], 0, 0, 0);
            }
        }
        int hcol = wv * 16 + r16;     // h in [0,128)
        float bias0 = b2[hcol], bias1 = b2[128 + hcol], bias2 = b2[256 + hcol];
#pragma unroll
        for (int m = 0; m < 4; ++m) {
            float2 pf[4];
#pragma unroll
            for (int j = 0; j < 4; ++j) pf[j] = pfE[m * 16 + rq + j];
#pragma unroll
            for (int j = 0; j < 4; ++j) {
                int r = m * 16 + rq + j;
                int g = row0 + r;
                if (g < NROWS) {
                    float vi = fminf(fmaxf((acc[m][0][j] + bias0) * (1.0f / 3.0f) + 0.5f, 0.0f), 1.0f);
                    float pl = pf[j].x * vi;
                    float ev = pf[j].y * fmaxf(acc[m][1][j] + bias1, 0.0f);
                    float vmv = __expf(acc[m][2][j] + bias2);
                    unsigned pk = (unsigned)f2bf(pl - ev) | ((unsigned)f2bf(vmv) << 16);
                    NVu[(size_t)g * 128 + hcol] = pk;
                }
            }
        }
    }
}

// ---------------- K3: role+tap split scan; SGPR PT; 16-step reduce ----------------
// TAPOFF: 0 -> conv taps 0..3 (FMA into a0..a3); 4 -> taps 4..7 (FMA into a4..a7)
template<int TAPOFF, int ISC>
__device__ __forceinline__ void scan_loop(
    int lane, int s, int outslot,
    float kp, float ks, float kg, float gp, float gpc, float gL, float kpgl, float qb,
    float r0, float r1, float r2, float r3,
    float cpw0, float cpw1, float cpb, float csw0, float csw1, float csb,
    float cgw0, float cgw1, float cgb,
    const unsigned* __restrict__ nvbase, const float4* __restrict__ PTg,
    float (*red)[68], float* __restrict__ outp)
{
    float Sf = 0.0f, Ss = 0.0f, Sg = 0.0f;
    float a0 = 0, a1 = 0, a2 = 0, a3 = 0, a4 = 0, a5 = 0, a6 = 0, a7 = 0;
    unsigned nv[16];
#pragma unroll
    for (int i = 0; i < 16; ++i) nv[i] = nvbase[(size_t)i * NSS * 128];
    // wave-uniform PT ring -> scalar loads (all-SGPR addressing)
    float4 pt[8];
#pragma unroll
    for (int i = 0; i < 8; ++i) pt[i] = PTg[(size_t)i * NSS + s];

    for (int tb = 0; tb < 368; tb += 16) {
#pragma unroll
        for (int u = 0; u < 16; ++u) {
            int t = tb + u;
            unsigned nvu = nv[u];
            float net = __builtin_bit_cast(float, nvu << 16);
            float vm  = __builtin_bit_cast(float, nvu & 0xFFFF0000u);
            nv[u] = nvbase[(size_t)(t + 16) * NSS * 128];
            float psv = pt[u & 7].x, T1 = pt[u & 7].y, T2 = pt[u & 7].z;
            pt[u & 7] = PTg[(size_t)(t + 8) * NSS + s];
            float t1v = Sf + psv;
            float qf = fminf(t1v, vm);
            Sf = fmaxf(t1v - vm, 0.0f);
            float H = fmaxf(Ss + qf + net, 0.0f);
            float qp = fmaxf(kp * H - kpgl, 0.0f);
            float qs = ks * fminf(H, gL);
            Ss = H - qp - qs;
            float qso = qs * gpc;
            float qsg = qs * gp;
            float tg = Sg + qsg;
            float qg = kg * tg + qb;
            Sg = tg - qg;
            float val;
            if (ISC) {
                float cp = exp2f(cpw0 * T1 + cpw1 * T2 + cpb);
                float cs = exp2f(csw0 * T1 + csw1 * T2 + csb);
                float cg = exp2f(cgw0 * T1 + cgw1 * T2 + cgb);
                val = qp * cp + qso * cs + qg * cg;
            } else {
                val = qp + qso + qg;
            }
            if (TAPOFF == 0) {
                a0 += val * r0; a1 += val * r1; a2 += val * r2; a3 += val * r3;
            } else {
                a4 += val * r0; a5 += val * r1; a6 += val * r2; a7 += val * r3;
            }
            red[u][lane] = a0;
            a0 = a1; a1 = a2; a2 = a3; a3 = a4; a4 = a5; a5 = a6; a6 = a7; a7 = 0.0f;
            if (u == 15) {
                int v = lane >> 2, sub = lane & 3;    // v = step row 0..15
                const float4* rp4 = (const float4*)&red[v][0];
                float4 x0 = rp4[sub * 4 + 0];
                float4 x1 = rp4[sub * 4 + 1];
                float4 x2 = rp4[sub * 4 + 2];
                float4 x3 = rp4[sub * 4 + 3];
                float sA = (x0.x + x0.y) + (x0.z + x0.w);
                float sB = (x1.x + x1.y) + (x1.z + x1.w);
                float sC = (x2.x + x2.y) + (x2.z + x2.w);
                float sD = (x3.x + x3.y) + (x3.z + x3.w);
                float sm = (sA + sB) + (sC + sD);
                sm += __shfl_xor(sm, 1);
                sm += __shfl_xor(sm, 2);
                int tt = tb + v;
                if (sub == 0 && tt < NTT)
                    outp[((size_t)tt * NSS + s) * 4 + outslot] = sm;
            }
        }
    }
}

__global__ __launch_bounds__(64) void k_scan(
    const float* __restrict__ wsite, const float* __restrict__ rsite,
    const float* __restrict__ gaw,
    const float* __restrict__ ctp8, const float* __restrict__ ctpb,
    const float4* __restrict__ PTg, const unsigned* __restrict__ NVu,
    float* __restrict__ pQ, float* __restrict__ pC)
{
    __shared__ __align__(16) float red[16][68];    // 4352 B
    int lane = threadIdx.x;
    int b = blockIdx.x;                 // b = ((s*2 + isc)*2 + half)*2 + tg
    int tg  = b & 1;
    int half = (b >> 1) & 1;
    int isc = (b >> 2) & 1;
    int s = b >> 3;
    int h = half * 64 + lane;
    int outslot = half * 2 + tg;

    const float* wrow = wsite + s * 896;
    float kp = sigf(wrow[0 * 128 + h]);
    float ks = sigf(wrow[1 * 128 + h]);
    float kg = sigf(wrow[2 * 128 + h]);
    float gp = sigf(wrow[3 * 128 + h]);
    float gpc = 1.0f - gp;
    float gL = __expf(wrow[4 * 128 + h]) * 2.0f;
    float kpgl = kp * gL;
    float qb = fmaxf(wrow[5 * 128 + h], 0.0f);
    float ga = gaw[s * 128 + h];
    float4 rr = *(const float4*)(rsite + s * 1024 + h * 8 + tg * 4);
    float r0 = fmaxf(rr.x, 0.0f) * ga;
    float r1 = fmaxf(rr.y, 0.0f) * ga;
    float r2 = fmaxf(rr.z, 0.0f) * ga;
    float r3 = fmaxf(rr.w, 0.0f) * ga;

    const unsigned* nvbase = NVu + (size_t)s * 128 + h;

    if (isc == 0) {
        if (tg == 0)
            scan_loop<0, 0>(lane, s, outslot, kp, ks, kg, gp, gpc, gL, kpgl, qb,
                            r0, r1, r2, r3, 0.f, 0.f, 0.f, 0.f, 0.f, 0.f, 0.f, 0.f, 0.f,
                            nvbase, PTg, red, pQ);
        else
            scan_loop<4, 0>(lane, s, outslot, kp, ks, kg, gp, gpc, gL, kpgl, qb,
                            r0, r1, r2, r3, 0.f, 0.f, 0.f, 0.f, 0.f, 0.f, 0.f, 0.f, 0.f,
                            nvbase, PTg, red, pQ);
    } else {
        const float4* cp4 = (const float4*)(ctp8 + ((size_t)s * 128 + h) * 8);
        float4 c0 = cp4[0], c1 = cp4[1];
        float cgb = ctpb[(size_t)s * 128 + h];
        if (tg == 0)
            scan_loop<0, 1>(lane, s, outslot, kp, ks, kg, gp, gpc, gL, kpgl, qb,
                            r0, r1, r2, r3,
                            c0.x, c0.y, c0.z, c0.w, c1.x, c1.y, c1.z, c1.w, cgb,
                            nvbase, PTg, red, pC);
        else
            scan_loop<4, 1>(lane, s, outslot, kp, ks, kg, gp, gpc, gL, kpgl, qb,
                            r0, r1, r2, r3,
                            c0.x, c0.y, c0.z, c0.w, c1.x, c1.y, c1.z, c1.w, cgb,
                            nvbase, PTg, red, pC);
    }
}

// ---------------- K4: combine 4 partials per stream, divide ----------------
__global__ __launch_bounds__(256) void k_final(const float* __restrict__ pQ,
                                               const float* __restrict__ pC,
                                               float* __restrict__ out)
{
    int i = blockIdx.x * 256 + threadIdx.x;
    if (i < NROWS) {
        float4 q4 = *(const float4*)(pQ + (size_t)i * 4);
        float4 c4 = *(const float4*)(pC + (size_t)i * 4);
        float q = (q4.x + q4.y) + (q4.z + q4.w);
        float c = (c4.x + c4.y) + (c4.z + c4.w);
        out[i] = q;
        out[NROWS + i] = c / q;
    }
}

extern "C" void kernel_launch(void* const* d_in, const int* in_sizes, int n_in,
                              void* d_out, int out_size, void* d_ws, size_t ws_size,
                              hipStream_t stream)
{
    const float* x      = (const float*)d_in[0];
    const float* xc     = (const float*)d_in[1];
    const float* fcR_w1 = (const float*)d_in[2];
    const float* fcR_b1 = (const float*)d_in[3];
    const float* fcR_w2 = (const float*)d_in[4];
    const float* fcR_b2 = (const float*)d_in[5];
    const float* fcW_w1 = (const float*)d_in[6];
    const float* fcW_b1 = (const float*)d_in[7];
    const float* fcW_w2 = (const float*)d_in[8];
    const float* fcW_b2 = (const float*)d_in[9];
    const float* fcT_w1 = (const float*)d_in[10];
    const float* fcT_b1 = (const float*)d_in[11];
    const float* fcT_w2 = (const float*)d_in[12];
    const float* fcT_b2 = (const float*)d_in[13];
    const float* fcCT_w = (const float*)d_in[14];
    const float* fcCT_b = (const float*)d_in[15];
    float* out = (float*)d_out;

    float* ws = (float*)d_ws;
    size_t o_w    = 0;                                   // 300*896
    size_t o_r    = o_w  + 300 * 896;                    // 300*1024
    size_t o_ga   = o_r  + 300 * 1024;                   // 300*128
    size_t o_PT   = o_ga + 300 * 128;                    // TPAD*300 float4
    size_t o_NV   = o_PT + (size_t)TPAD * NSS * 4;       // TPAD*300*128 u32
    size_t o_pQ   = o_NV + (size_t)TPAD * NSS * 128;     // NROWS*4
    size_t o_pC   = o_pQ + (size_t)NROWS * 4;            // NROWS*4
    size_t o_w1bf = o_pC + (size_t)NROWS * 4;
    size_t o_w2bf = o_w1bf + 8192;
    size_t o_ctp  = o_w2bf + 49152;                      // 300*128*8
    size_t o_ctpb = o_ctp + (size_t)300 * 128 * 8;       // 300*128

    float* wsite = ws + o_w;
    float* rsite = ws + o_r;
    float* gaw   = ws + o_ga;
    float4* PT   = (float4*)(ws + o_PT);
    unsigned* NVu = (unsigned*)(ws + o_NV);
    float* pQ    = ws + o_pQ;
    float* pC    = ws + o_pC;
    unsigned short* w1s = (unsigned short*)(ws + o_w1bf);
    unsigned short* w2s = (unsigned short*)(ws + o_w2bf);
    float* ctp8  = ws + o_ctp;
    float* ctpb  = ws + o_ctpb;

    k_prep<<<56, 256, 0, stream>>>(fcT_w1, fcT_w2, w1s, w2s);
    k_site<<<dim3(30, 8), 256, 0, stream>>>(xc, fcW_w1, fcW_b1, fcW_w2, fcW_b2,
                                            fcR_w1, fcR_b1, fcR_w2, fcR_b2, wsite, rsite);
    k_softmax_ga<<<300, 128, 0, stream>>>(wsite, gaw);
    k_ct<<<300, 128, 0, stream>>>(xc, fcCT_w, fcCT_b, ctp8, ctpb);
    int nblk2 = (NROWS + 63) / 64;   // 1711
    k_fcT<<<nblk2, 512, 0, stream>>>(x, xc, w1s, fcT_b1, w2s, fcT_b2, PT, NVu);
    k_scan<<<2400, 64, 0, stream>>>(wsite, rsite, gaw, ctp8, ctpb,
                                    PT, NVu, pQ, pC);
    k_final<<<(NROWS + 255) / 256, 256, 0, stream>>>(pQ, pC, out);
}

// Round 8
// 175.621 us; speedup vs baseline: 1.2119x; 1.2119x over previous
//
#include <hip/hip_runtime.h>
#include <math.h>

#define NTT 365
#define NSS 300
#define NROWS (NTT*NSS)   // 109500
#define TPAD2 416         // padded time steps (32-step pipelined scan + 16 prefetch + 4 pt)

using bf16x8 = __attribute__((ext_vector_type(8))) short;
using f32x4  = __attribute__((ext_vector_type(4))) float;

__device__ __forceinline__ float sigf(float v) { return 1.0f / (1.0f + __expf(-v)); }

__device__ __forceinline__ float tanhfast(float x) {
    float e = __expf(2.0f * x);
    return 1.0f - 2.0f * __builtin_amdgcn_rcpf(1.0f + e);
}

__device__ __forceinline__ unsigned short f2bf(float f) {
    unsigned u = __builtin_bit_cast(unsigned, f);
    u += 0x7FFFu + ((u >> 16) & 1u);
    return (unsigned short)(u >> 16);
}

// ---------------- K0: swizzle fcT weights to fragment-major bf16 ----------------
__global__ __launch_bounds__(256) void k_prep(const float* __restrict__ w1,
                                              const float* __restrict__ w2,
                                              unsigned short* __restrict__ w1s,
                                              unsigned short* __restrict__ w2s)
{
    int G = blockIdx.x * 256 + threadIdx.x;
    if (G < 2048) {
        int lane = G & 63, ks = (G >> 6) & 1, tile = G >> 7;
        int o = tile * 16 + (lane & 15);
        int kb = ks * 32 + (lane >> 4) * 8;
        unsigned short tmp[8];
#pragma unroll
        for (int e = 0; e < 8; ++e) {
            int k = kb + e;
            tmp[e] = (k < 38) ? f2bf(w1[o * 38 + k]) : (unsigned short)0;
        }
        *(bf16x8*)(w1s + (size_t)G * 8) = *(bf16x8*)tmp;
    } else if (G < 2048 + 12288) {
        int G2 = G - 2048;
        int lane = G2 & 63, ks = (G2 >> 6) & 7, tile = G2 >> 9;
        int o = tile * 16 + (lane & 15);
        int kb = ks * 32 + (lane >> 4) * 8;
        unsigned short tmp[8];
#pragma unroll
        for (int e = 0; e < 8; ++e) tmp[e] = f2bf(w2[o * 256 + kb + e]);
        *(bf16x8*)(w2s + (size_t)G2 * 8) = *(bf16x8*)tmp;
    }
}

// ---------------- K1: per-site MLPs, output-sliced grid (30 x 8) ----------------
__global__ __launch_bounds__(256) void k_site(
    const float* __restrict__ xc,
    const float* __restrict__ wW1, const float* __restrict__ bW1,
    const float* __restrict__ wW2, const float* __restrict__ bW2,
    const float* __restrict__ wR1, const float* __restrict__ bR1,
    const float* __restrict__ wR2, const float* __restrict__ bR2,
    float* __restrict__ wsite, float* __restrict__ rsite)
{
    __shared__ float xcb[10][32];
    __shared__ float hW[10][256];
    __shared__ float hR[10][256];
    int tid = threadIdx.x;
    int s0 = blockIdx.x * 10;
    int os = blockIdx.y;              // 0..7 output slice
    for (int i = tid; i < 10 * 32; i += 256) xcb[i / 32][i % 32] = xc[s0 * 32 + i];
    __syncthreads();
    {
        int j = tid;
        float aW[10], aR[10];
#pragma unroll
        for (int r = 0; r < 10; ++r) { aW[r] = bW1[j]; aR[r] = bR1[j]; }
        for (int k = 0; k < 32; ++k) {
            float wv = wW1[j * 32 + k], rv = wR1[j * 32 + k];
#pragma unroll
            for (int r = 0; r < 10; ++r) { float xv = xcb[r][k]; aW[r] += xv * wv; aR[r] += xv * rv; }
        }
#pragma unroll
        for (int r = 0; r < 10; ++r) { hW[r][j] = tanhfast(aW[r]); hR[r][j] = tanhfast(aR[r]); }
    }
    __syncthreads();
    if (tid < 240) {
        int o_lin = os * 240 + tid;   // 0..1919
        float acc[10];
        if (o_lin < 896) {
            int o = o_lin;
#pragma unroll
            for (int r = 0; r < 10; ++r) acc[r] = bW2[o];
            for (int k = 0; k < 256; ++k) {
                float wv = wW2[o * 256 + k];
#pragma unroll
                for (int r = 0; r < 10; ++r) acc[r] += hW[r][k] * wv;
            }
#pragma unroll
            for (int r = 0; r < 10; ++r) wsite[(s0 + r) * 896 + o] = acc[r];
        } else {
            int o = o_lin - 896;      // 0..1023
#pragma unroll
            for (int r = 0; r < 10; ++r) acc[r] = bR2[o];
            for (int k = 0; k < 256; ++k) {
                float wv = wR2[o * 256 + k];
#pragma unroll
                for (int r = 0; r < 10; ++r) acc[r] += hR[r][k] * wv;
            }
#pragma unroll
            for (int r = 0; r < 10; ++r) rsite[(s0 + r) * 1024 + o] = acc[r];
        }
    }
}

// ---------------- K1b: softmax of ga over h per site ----------------
__global__ __launch_bounds__(128) void k_softmax_ga(const float* __restrict__ wsite,
                                                    float* __restrict__ ga)
{
    int s = blockIdx.x, tid = threadIdx.x;
    __shared__ float red[2];
    float v = wsite[s * 896 + 6 * 128 + tid];
    float m = v;
#pragma unroll
    for (int off = 32; off >= 1; off >>= 1) m = fmaxf(m, __shfl_xor(m, off));
    if ((tid & 63) == 0) red[tid >> 6] = m;
    __syncthreads();
    m = fmaxf(red[0], red[1]);
    __syncthreads();
    float e = __expf(v - m);
    float ssum = e;
#pragma unroll
    for (int off = 32; off >= 1; off >>= 1) ssum += __shfl_xor(ssum, off);
    if ((tid & 63) == 0) red[tid >> 6] = ssum;
    __syncthreads();
    ssum = red[0] + red[1];
    ga[s * 128 + tid] = e / ssum;
}

// ---------------- K1c: precompute ct gate params per (s,h) ----------------
__global__ __launch_bounds__(128) void k_ct(const float* __restrict__ xc,
                                            const float* __restrict__ ctw,
                                            const float* __restrict__ ctb,
                                            float* __restrict__ ctp8,
                                            float* __restrict__ ctpb)
{
    __shared__ float xcs[32];
    int s = blockIdx.x, h = threadIdx.x;
    if (h < 32) xcs[h] = xc[s * 32 + h];
    __syncthreads();
    const float L2E = 1.4426950408889634f;
    const float LG01 = -3.3219280948873623f;   // log2(0.1): folds /10 into cp
    float out[8];
    float cgb = 0.0f;
#pragma unroll
    for (int g = 0; g < 3; ++g) {
        const float* wr = ctw + (g * 128 + h) * 34;
        float base = ctb[g * 128 + h];
        for (int k = 0; k < 32; ++k) base += wr[2 + k] * xcs[k];
        float w0 = wr[0] * L2E, w1 = wr[1] * L2E;
        float bb = base * L2E + ((g == 0) ? LG01 : 0.0f);
        if (g == 0) { out[0] = w0; out[1] = w1; out[2] = bb; }
        else if (g == 1) { out[3] = w0; out[4] = w1; out[5] = bb; }
        else { out[6] = w0; out[7] = w1; cgb = bb; }
    }
    float4* dst = (float4*)(ctp8 + ((size_t)s * 128 + h) * 8);
    dst[0] = make_float4(out[0], out[1], out[2], out[3]);
    dst[1] = make_float4(out[4], out[5], out[6], out[7]);
    ctpb[(size_t)s * 128 + h] = cgb;
}

// ---------------- K2: fcT MLP via bf16 MFMA -> PTt[s][t], NVu[s][t][h] ----------------
__global__ __launch_bounds__(512) void k_fcT(
    const float* __restrict__ x, const float* __restrict__ xc,
    const unsigned short* __restrict__ w1s, const float* __restrict__ b1,
    const unsigned short* __restrict__ w2s, const float* __restrict__ b2,
    float4* __restrict__ PTt, unsigned* __restrict__ NVu)
{
    __shared__ unsigned short A1[64][72];
    __shared__ unsigned short hb[64][264];
    __shared__ float2 pfE[64];           // {P*(1-vf), 2*E}
    int tid = threadIdx.x;
    int row0 = blockIdx.x * 64;

    for (int idx = tid; idx < 64 * 64; idx += 512) {
        int r = idx >> 6, c = idx & 63;
        int g = row0 + r;
        float val = 0.0f;
        if (g < NROWS) {
            if (c < 6) val = x[g * 6 + c];
            else if (c < 38) { int s = g % NSS; val = xc[s * 32 + (c - 6)]; }
        }
        A1[r][c] = f2bf(val);
    }
    if (tid < 64) {
        int r = tid, g = row0 + r;
        float P = 0, E = 0, T1 = 0, T2 = 0;
        if (g < NROWS) { P = x[g * 6]; E = x[g * 6 + 1]; T1 = x[g * 6 + 2]; T2 = x[g * 6 + 3]; }
        float den = T2 - T1;
        float dg = (den == 0.0f) ? 1.0f : den;
        float ratio = fminf(fmaxf((T1 + T2) / dg, -1.0f), 1.0f);
        float vf = acosf(ratio) * (1.0f / 3.1415f);
        vf = (T1 >= 0.0f) ? 0.0f : ((T2 <= 0.0f) ? 1.0f : vf);
        pfE[r] = make_float2(P * (1.0f - vf), 2.0f * E);
        if (g < NROWS) {
            int tg = g / NSS, sg = g - tg * NSS;
            PTt[(size_t)sg * TPAD2 + tg] = make_float4(P * vf, T1, T2, vf);
        }
    }
    __syncthreads();

    int lane = tid & 63, wv = tid >> 6;
    int r16 = lane & 15;
    int kg = (lane >> 4) * 8;     // k offset within 32-chunk
    int rq = (lane >> 4) * 4;     // row offset of C frag

    // ---- layer 1: [64 x 64(Kpad)] @ [256 x 64]^T -> hidden (bf16) ----
    {
        int mt = wv & 3, nb = (wv >> 2) * 8;
        f32x4 acc[8];
#pragma unroll
        for (int i = 0; i < 8; ++i) acc[i] = (f32x4){0.f, 0.f, 0.f, 0.f};
#pragma unroll
        for (int ks = 0; ks < 2; ++ks) {
            bf16x8 a = *(const bf16x8*)&A1[mt * 16 + r16][ks * 32 + kg];
#pragma unroll
            for (int i = 0; i < 8; ++i) {
                bf16x8 b = *(const bf16x8*)(w1s + ((size_t)(((nb + i) * 2 + ks) * 64 + lane) << 3));
                acc[i] = __builtin_amdgcn_mfma_f32_16x16x32_bf16(a, b, acc[i], 0, 0, 0);
            }
        }
#pragma unroll
        for (int i = 0; i < 8; ++i) {
            int col = (nb + i) * 16 + r16;
            float bias = b1[col];
#pragma unroll
            for (int j = 0; j < 4; ++j) {
                int row = mt * 16 + rq + j;
                hb[row][col] = f2bf(tanhfast(acc[i][j] + bias));
            }
        }
    }
    __syncthreads();

    // ---- layer 2: [64 x 256] @ [384 x 256]^T, wave w -> col tiles {w, w+8, w+16} ----
    {
        int t0 = wv, t1 = wv + 8, t2 = wv + 16;
        f32x4 acc[4][3];
#pragma unroll
        for (int m = 0; m < 4; ++m)
#pragma unroll
            for (int c = 0; c < 3; ++c) acc[m][c] = (f32x4){0.f, 0.f, 0.f, 0.f};
#pragma unroll
        for (int ks = 0; ks < 8; ++ks) {
            bf16x8 b0 = *(const bf16x8*)(w2s + ((size_t)((t0 * 8 + ks) * 64 + lane) << 3));
            bf16x8 b1v = *(const bf16x8*)(w2s + ((size_t)((t1 * 8 + ks) * 64 + lane) << 3));
            bf16x8 b2v = *(const bf16x8*)(w2s + ((size_t)((t2 * 8 + ks) * 64 + lane) << 3));
#pragma unroll
            for (int m = 0; m < 4; ++m) {
                bf16x8 a = *(const bf16x8*)&hb[m * 16 + r16][ks * 32 + kg];
                acc[m][0] = __builtin_amdgcn_mfma_f32_16x16x32_bf16(a, b0, acc[m][0], 0, 0, 0);
                acc[m][1] = __builtin_amdgcn_mfma_f32_16x16x32_bf16(a, b1v, acc[m][1], 0, 0, 0);
                acc[m][2] = __builtin_amdgcn_mfma_f32_16x16x32_bf16(a, b2v, acc[m][2], 0, 0, 0);
            }
        }
        int hcol = wv * 16 + r16;     // h in [0,128)
        float bias0 = b2[hcol], bias1 = b2[128 + hcol], bias2 = b2[256 + hcol];
#pragma unroll
        for (int m = 0; m < 4; ++m) {
            float2 pf[4];
#pragma unroll
            for (int j = 0; j < 4; ++j) pf[j] = pfE[m * 16 + rq + j];
#pragma unroll
            for (int j = 0; j < 4; ++j) {
                int r = m * 16 + rq + j;
                int g = row0 + r;
                if (g < NROWS) {
                    float vi = fminf(fmaxf((acc[m][0][j] + bias0) * (1.0f / 3.0f) + 0.5f, 0.0f), 1.0f);
                    float pl = pf[j].x * vi;
                    float ev = pf[j].y * fmaxf(acc[m][1][j] + bias1, 0.0f);
                    float vmv = __expf(acc[m][2][j] + bias2);
                    unsigned pk = (unsigned)f2bf(pl - ev) | ((unsigned)f2bf(vmv) << 16);
                    int tg = g / NSS, sg = g - tg * NSS;
                    NVu[((size_t)sg * TPAD2 + tg) * 128 + hcol] = pk;
                }
            }
        }
    }
}

// ---------------- K3: role-split scan; ping-pong register prefetch ----------------
template<int ISC>
__device__ __forceinline__ void scan_loop(
    int lane, int s, int half,
    float kp, float ks, float kg, float gp, float gpc, float gL, float kpgl, float qb,
    float r0, float r1, float r2, float r3, float r4, float r5, float r6, float r7,
    float cpw0, float cpw1, float cpb, float csw0, float csw1, float csb,
    float cgw0, float cgw1, float cgb,
    const unsigned* __restrict__ nvsite, const float4* ptlds, float (*red)[68],
    float* __restrict__ outp)
{
    float Sf = 0.0f, Ss = 0.0f, Sg = 0.0f;
    float a0 = 0, a1 = 0, a2 = 0, a3 = 0, a4 = 0, a5 = 0, a6 = 0, a7 = 0;
    unsigned A[16], B[16];
    float4 pt[4];
#pragma unroll
    for (int i = 0; i < 16; ++i) A[i] = nvsite[(size_t)i * 128];
#pragma unroll
    for (int i = 0; i < 4; ++i) pt[i] = ptlds[i];

    auto STEP = [&](int t, int uu, unsigned nvu, unsigned& pref) {
        pref = nvsite[(size_t)(t + 16) * 128];     // 16-deep prefetch, disjoint buffer
        float net = __builtin_bit_cast(float, nvu << 16);
        float vm  = __builtin_bit_cast(float, nvu & 0xFFFF0000u);
        int ps = uu & 3;
        float psv = pt[ps].x, T1 = pt[ps].y, T2 = pt[ps].z;
        pt[ps] = ptlds[t + 4];
        float t1v = Sf + psv;
        float qf = fminf(t1v, vm);
        Sf = fmaxf(t1v - vm, 0.0f);
        float H = fmaxf(Ss + qf + net, 0.0f);
        float qp = fmaxf(kp * H - kpgl, 0.0f);
        float qs = ks * fminf(H, gL);
        Ss = H - qp - qs;
        float qso = qs * gpc;
        float qsg = qs * gp;
        float tg2 = Sg + qsg;
        float qg = kg * tg2 + qb;
        Sg = tg2 - qg;
        float val;
        if (ISC) {
            float cp = exp2f(cpw0 * T1 + cpw1 * T2 + cpb);
            float cs = exp2f(csw0 * T1 + csw1 * T2 + csb);
            float cg = exp2f(cgw0 * T1 + cgw1 * T2 + cgb);
            val = qp * cp + qso * cs + qg * cg;
        } else {
            val = qp + qso + qg;
        }
        a0 += val * r0; a1 += val * r1; a2 += val * r2; a3 += val * r3;
        a4 += val * r4; a5 += val * r5; a6 += val * r6; a7 += val * r7;
        red[uu & 15][lane] = a0;
        a0 = a1; a1 = a2; a2 = a3; a3 = a4; a4 = a5; a5 = a6; a6 = a7; a7 = 0.0f;
    };

    auto RED = [&](int base) {
        int v = lane >> 2, sub = lane & 3;    // v = step row 0..15
        const float4* rp4 = (const float4*)&red[v][0];
        float4 x0 = rp4[sub * 4 + 0];
        float4 x1 = rp4[sub * 4 + 1];
        float4 x2 = rp4[sub * 4 + 2];
        float4 x3 = rp4[sub * 4 + 3];
        float sA = (x0.x + x0.y) + (x0.z + x0.w);
        float sB = (x1.x + x1.y) + (x1.z + x1.w);
        float sC = (x2.x + x2.y) + (x2.z + x2.w);
        float sD = (x3.x + x3.y) + (x3.z + x3.w);
        float sm = (sA + sB) + (sC + sD);
        sm += __shfl_xor(sm, 1);
        sm += __shfl_xor(sm, 2);
        int tt = base + v;
        if (sub == 0 && tt < NTT)
            outp[((size_t)tt * NSS + s) * 2 + half] = sm;
    };

    for (int tb = 0; tb < 384; tb += 32) {
#pragma unroll
        for (int u = 0; u < 16; ++u) STEP(tb + u, u, A[u], B[u]);
        RED(tb);
#pragma unroll
        for (int u = 0; u < 16; ++u) STEP(tb + 16 + u, u + 16, B[u], A[u]);
        RED(tb + 16);
    }
}

__global__ __launch_bounds__(64) void k_scan(
    const float* __restrict__ wsite, const float* __restrict__ rsite,
    const float* __restrict__ gaw,
    const float* __restrict__ ctp8, const float* __restrict__ ctpb,
    const float4* __restrict__ PTt, const unsigned* __restrict__ NVu,
    float* __restrict__ pQ, float* __restrict__ pC)
{
    __shared__ float4 ptlds[TPAD2];                // 6656 B
    __shared__ __align__(16) float red[16][68];    // 4352 B
    int lane = threadIdx.x;
    int b = blockIdx.x;
    // XCD-grouped: all 4 (half,role) blocks of a site -> same XCD (b mod 8 equal)
    int s = (b >> 5) * 8 + (b & 7);
    int hr = (b >> 3) & 3;
    int half = hr >> 1, role = hr & 1;
    if (s >= NSS) return;
    int h = half * 64 + lane;

    // one-time PT stage from [s][t] layout (coalesced); single wave -> no barrier
    for (int t = lane; t < TPAD2; t += 64) ptlds[t] = PTt[(size_t)s * TPAD2 + t];

    const float* wrow = wsite + s * 896;
    float kp = sigf(wrow[0 * 128 + h]);
    float ks = sigf(wrow[1 * 128 + h]);
    float kg = sigf(wrow[2 * 128 + h]);
    float gp = sigf(wrow[3 * 128 + h]);
    float gpc = 1.0f - gp;
    float gL = __expf(wrow[4 * 128 + h]) * 2.0f;
    float kpgl = kp * gL;
    float qb = fmaxf(wrow[5 * 128 + h], 0.0f);
    float ga = gaw[s * 128 + h];
    float4 rrA = *(const float4*)(rsite + s * 1024 + h * 8);
    float4 rrB = *(const float4*)(rsite + s * 1024 + h * 8 + 4);
    float r0 = fmaxf(rrA.x, 0.0f) * ga;
    float r1 = fmaxf(rrA.y, 0.0f) * ga;
    float r2 = fmaxf(rrA.z, 0.0f) * ga;
    float r3 = fmaxf(rrA.w, 0.0f) * ga;
    float r4 = fmaxf(rrB.x, 0.0f) * ga;
    float r5 = fmaxf(rrB.y, 0.0f) * ga;
    float r6 = fmaxf(rrB.z, 0.0f) * ga;
    float r7 = fmaxf(rrB.w, 0.0f) * ga;

    const unsigned* nvsite = NVu + (size_t)s * TPAD2 * 128 + h;

    if (role == 0) {
        scan_loop<0>(lane, s, half, kp, ks, kg, gp, gpc, gL, kpgl, qb,
                     r0, r1, r2, r3, r4, r5, r6, r7,
                     0.f, 0.f, 0.f, 0.f, 0.f, 0.f, 0.f, 0.f, 0.f,
                     nvsite, ptlds, red, pQ);
    } else {
        const float4* cp4 = (const float4*)(ctp8 + ((size_t)s * 128 + h) * 8);
        float4 c0 = cp4[0], c1 = cp4[1];
        float cgb = ctpb[(size_t)s * 128 + h];
        scan_loop<1>(lane, s, half, kp, ks, kg, gp, gpc, gL, kpgl, qb,
                     r0, r1, r2, r3, r4, r5, r6, r7,
                     c0.x, c0.y, c0.z, c0.w, c1.x, c1.y, c1.z, c1.w, cgb,
                     nvsite, ptlds, red, pC);
    }
}

// ---------------- K4: combine halves, divide ----------------
__global__ __launch_bounds__(256) void k_final(const float* __restrict__ pQ,
                                               const float* __restrict__ pC,
                                               float* __restrict__ out)
{
    int i = blockIdx.x * 256 + threadIdx.x;
    if (i < NROWS) {
        float q = pQ[i * 2] + pQ[i * 2 + 1];
        float c = pC[i * 2] + pC[i * 2 + 1];
        out[i] = q;
        out[NROWS + i] = c / q;
    }
}

extern "C" void kernel_launch(void* const* d_in, const int* in_sizes, int n_in,
                              void* d_out, int out_size, void* d_ws, size_t ws_size,
                              hipStream_t stream)
{
    const float* x      = (const float*)d_in[0];
    const float* xc     = (const float*)d_in[1];
    const float* fcR_w1 = (const float*)d_in[2];
    const float* fcR_b1 = (const float*)d_in[3];
    const float* fcR_w2 = (const float*)d_in[4];
    const float* fcR_b2 = (const float*)d_in[5];
    const float* fcW_w1 = (const float*)d_in[6];
    const float* fcW_b1 = (const float*)d_in[7];
    const float* fcW_w2 = (const float*)d_in[8];
    const float* fcW_b2 = (const float*)d_in[9];
    const float* fcT_w1 = (const float*)d_in[10];
    const float* fcT_b1 = (const float*)d_in[11];
    const float* fcT_w2 = (const float*)d_in[12];
    const float* fcT_b2 = (const float*)d_in[13];
    const float* fcCT_w = (const float*)d_in[14];
    const float* fcCT_b = (const float*)d_in[15];
    float* out = (float*)d_out;

    float* ws = (float*)d_ws;
    size_t o_w    = 0;                                     // 300*896
    size_t o_r    = o_w  + 300 * 896;                      // 300*1024
    size_t o_ga   = o_r  + 300 * 1024;                     // 300*128
    size_t o_PT   = o_ga + 300 * 128;                      // NSS*TPAD2 float4
    size_t o_NV   = o_PT + (size_t)TPAD2 * NSS * 4;        // NSS*TPAD2*128 u32
    size_t o_pQ   = o_NV + (size_t)TPAD2 * NSS * 128;      // NROWS*2
    size_t o_pC   = o_pQ + (size_t)NROWS * 2;              // NROWS*2
    size_t o_w1bf = o_pC + (size_t)NROWS * 2;
    size_t o_w2bf = o_w1bf + 8192;
    size_t o_ctp  = o_w2bf + 49152;                        // 300*128*8
    size_t o_ctpb = o_ctp + (size_t)300 * 128 * 8;         // 300*128

    float* wsite = ws + o_w;
    float* rsite = ws + o_r;
    float* gaw   = ws + o_ga;
    float4* PTt  = (float4*)(ws + o_PT);
    unsigned* NVu = (unsigned*)(ws + o_NV);
    float* pQ    = ws + o_pQ;
    float* pC    = ws + o_pC;
    unsigned short* w1s = (unsigned short*)(ws + o_w1bf);
    unsigned short* w2s = (unsigned short*)(ws + o_w2bf);
    float* ctp8  = ws + o_ctp;
    float* ctpb  = ws + o_ctpb;

    k_prep<<<56, 256, 0, stream>>>(fcT_w1, fcT_w2, w1s, w2s);
    k_site<<<dim3(30, 8), 256, 0, stream>>>(xc, fcW_w1, fcW_b1, fcW_w2, fcW_b2,
                                            fcR_w1, fcR_b1, fcR_w2, fcR_b2, wsite, rsite);
    k_softmax_ga<<<300, 128, 0, stream>>>(wsite, gaw);
    k_ct<<<300, 128, 0, stream>>>(xc, fcCT_w, fcCT_b, ctp8, ctpb);
    int nblk2 = (NROWS + 63) / 64;   // 1711
    k_fcT<<<nblk2, 512, 0, stream>>>(x, xc, w1s, fcT_b1, w2s, fcT_b2, PTt, NVu);
    // 300 sites x {half,role}: grouped so one site's 4 blocks share an XCD; 38*32=1216
    k_scan<<<1216, 64, 0, stream>>>(wsite, rsite, gaw, ctp8, ctpb,
                                    PTt, NVu, pQ, pC);
    k_final<<<(NROWS + 255) / 256, 256, 0, stream>>>(pQ, pC, out);
}

// Round 9
// 174.393 us; speedup vs baseline: 1.2205x; 1.0070x over previous
//
#include <hip/hip_runtime.h>
#include <math.h>

#define NTT 365
#define NSS 300
#define NROWS (NTT*NSS)   // 109500
#define TPAD2 416         // padded time steps (32-step pipelined scan + 16 prefetch + 4 pt)

using bf16x8 = __attribute__((ext_vector_type(8))) short;
using f32x4  = __attribute__((ext_vector_type(4))) float;

__device__ __forceinline__ float sigf(float v) { return 1.0f / (1.0f + __expf(-v)); }

__device__ __forceinline__ float tanhfast(float x) {
    float e = __expf(2.0f * x);
    return 1.0f - 2.0f * __builtin_amdgcn_rcpf(1.0f + e);
}

__device__ __forceinline__ unsigned short f2bf(float f) {
    unsigned u = __builtin_bit_cast(unsigned, f);
    u += 0x7FFFu + ((u >> 16) & 1u);
    return (unsigned short)(u >> 16);
}

// ---------------- K0: swizzle fcT weights to fragment-major bf16 ----------------
__global__ __launch_bounds__(256) void k_prep(const float* __restrict__ w1,
                                              const float* __restrict__ w2,
                                              unsigned short* __restrict__ w1s,
                                              unsigned short* __restrict__ w2s)
{
    int G = blockIdx.x * 256 + threadIdx.x;
    if (G < 2048) {
        int lane = G & 63, ks = (G >> 6) & 1, tile = G >> 7;
        int o = tile * 16 + (lane & 15);
        int kb = ks * 32 + (lane >> 4) * 8;
        unsigned short tmp[8];
#pragma unroll
        for (int e = 0; e < 8; ++e) {
            int k = kb + e;
            tmp[e] = (k < 38) ? f2bf(w1[o * 38 + k]) : (unsigned short)0;
        }
        *(bf16x8*)(w1s + (size_t)G * 8) = *(bf16x8*)tmp;
    } else if (G < 2048 + 12288) {
        int G2 = G - 2048;
        int lane = G2 & 63, ks = (G2 >> 6) & 7, tile = G2 >> 9;
        int o = tile * 16 + (lane & 15);
        int kb = ks * 32 + (lane >> 4) * 8;
        unsigned short tmp[8];
#pragma unroll
        for (int e = 0; e < 8; ++e) tmp[e] = f2bf(w2[o * 256 + kb + e]);
        *(bf16x8*)(w2s + (size_t)G2 * 8) = *(bf16x8*)tmp;
    }
}

// ---------------- K1: per-site MLPs, output-sliced grid (30 x 8) ----------------
__global__ __launch_bounds__(256) void k_site(
    const float* __restrict__ xc,
    const float* __restrict__ wW1, const float* __restrict__ bW1,
    const float* __restrict__ wW2, const float* __restrict__ bW2,
    const float* __restrict__ wR1, const float* __restrict__ bR1,
    const float* __restrict__ wR2, const float* __restrict__ bR2,
    float* __restrict__ wsite, float* __restrict__ rsite)
{
    __shared__ float xcb[10][32];
    __shared__ float hW[10][256];
    __shared__ float hR[10][256];
    int tid = threadIdx.x;
    int s0 = blockIdx.x * 10;
    int os = blockIdx.y;              // 0..7 output slice
    for (int i = tid; i < 10 * 32; i += 256) xcb[i / 32][i % 32] = xc[s0 * 32 + i];
    __syncthreads();
    {
        int j = tid;
        float aW[10], aR[10];
#pragma unroll
        for (int r = 0; r < 10; ++r) { aW[r] = bW1[j]; aR[r] = bR1[j]; }
        for (int k = 0; k < 32; ++k) {
            float wv = wW1[j * 32 + k], rv = wR1[j * 32 + k];
#pragma unroll
            for (int r = 0; r < 10; ++r) { float xv = xcb[r][k]; aW[r] += xv * wv; aR[r] += xv * rv; }
        }
#pragma unroll
        for (int r = 0; r < 10; ++r) { hW[r][j] = tanhfast(aW[r]); hR[r][j] = tanhfast(aR[r]); }
    }
    __syncthreads();
    if (tid < 240) {
        int o_lin = os * 240 + tid;   // 0..1919
        float acc[10];
        if (o_lin < 896) {
            int o = o_lin;
#pragma unroll
            for (int r = 0; r < 10; ++r) acc[r] = bW2[o];
            for (int k = 0; k < 256; ++k) {
                float wv = wW2[o * 256 + k];
#pragma unroll
                for (int r = 0; r < 10; ++r) acc[r] += hW[r][k] * wv;
            }
#pragma unroll
            for (int r = 0; r < 10; ++r) wsite[(s0 + r) * 896 + o] = acc[r];
        } else {
            int o = o_lin - 896;      // 0..1023
#pragma unroll
            for (int r = 0; r < 10; ++r) acc[r] = bR2[o];
            for (int k = 0; k < 256; ++k) {
                float wv = wR2[o * 256 + k];
#pragma unroll
                for (int r = 0; r < 10; ++r) acc[r] += hR[r][k] * wv;
            }
#pragma unroll
            for (int r = 0; r < 10; ++r) rsite[(s0 + r) * 1024 + o] = acc[r];
        }
    }
}

// ---------------- K1b: softmax of ga over h per site ----------------
__global__ __launch_bounds__(128) void k_softmax_ga(const float* __restrict__ wsite,
                                                    float* __restrict__ ga)
{
    int s = blockIdx.x, tid = threadIdx.x;
    __shared__ float red[2];
    float v = wsite[s * 896 + 6 * 128 + tid];
    float m = v;
#pragma unroll
    for (int off = 32; off >= 1; off >>= 1) m = fmaxf(m, __shfl_xor(m, off));
    if ((tid & 63) == 0) red[tid >> 6] = m;
    __syncthreads();
    m = fmaxf(red[0], red[1]);
    __syncthreads();
    float e = __expf(v - m);
    float ssum = e;
#pragma unroll
    for (int off = 32; off >= 1; off >>= 1) ssum += __shfl_xor(ssum, off);
    if ((tid & 63) == 0) red[tid >> 6] = ssum;
    __syncthreads();
    ssum = red[0] + red[1];
    ga[s * 128 + tid] = e / ssum;
}

// ---------------- K1c: precompute ct gate params per (s,h) ----------------
__global__ __launch_bounds__(128) void k_ct(const float* __restrict__ xc,
                                            const float* __restrict__ ctw,
                                            const float* __restrict__ ctb,
                                            float* __restrict__ ctp8,
                                            float* __restrict__ ctpb)
{
    __shared__ float xcs[32];
    int s = blockIdx.x, h = threadIdx.x;
    if (h < 32) xcs[h] = xc[s * 32 + h];
    __syncthreads();
    const float L2E = 1.4426950408889634f;
    const float LG01 = -3.3219280948873623f;   // log2(0.1): folds /10 into cp
    float out[8];
    float cgb = 0.0f;
#pragma unroll
    for (int g = 0; g < 3; ++g) {
        const float* wr = ctw + (g * 128 + h) * 34;
        float base = ctb[g * 128 + h];
        for (int k = 0; k < 32; ++k) base += wr[2 + k] * xcs[k];
        float w0 = wr[0] * L2E, w1 = wr[1] * L2E;
        float bb = base * L2E + ((g == 0) ? LG01 : 0.0f);
        if (g == 0) { out[0] = w0; out[1] = w1; out[2] = bb; }
        else if (g == 1) { out[3] = w0; out[4] = w1; out[5] = bb; }
        else { out[6] = w0; out[7] = w1; cgb = bb; }
    }
    float4* dst = (float4*)(ctp8 + ((size_t)s * 128 + h) * 8);
    dst[0] = make_float4(out[0], out[1], out[2], out[3]);
    dst[1] = make_float4(out[4], out[5], out[6], out[7]);
    ctpb[(size_t)s * 128 + h] = cgb;
}

// ---------------- K2: fcT MLP via bf16 MFMA -> PTt[s][t], NVu[s][t][h] ----------------
__global__ __launch_bounds__(512, 4) void k_fcT(
    const float* __restrict__ x, const float* __restrict__ xc,
    const unsigned short* __restrict__ w1s, const float* __restrict__ b1,
    const unsigned short* __restrict__ w2s, const float* __restrict__ b2,
    float4* __restrict__ PTt, unsigned* __restrict__ NVu)
{
    __shared__ unsigned short A1[64][72];
    __shared__ unsigned short hb[64][264];
    __shared__ float2 pfE[64];           // {P*(1-vf), 2*E}
    int tid = threadIdx.x;
    int row0 = blockIdx.x * 64;

    for (int idx = tid; idx < 64 * 64; idx += 512) {
        int r = idx >> 6, c = idx & 63;
        int g = row0 + r;
        float val = 0.0f;
        if (g < NROWS) {
            if (c < 6) val = x[g * 6 + c];
            else if (c < 38) { int s = g % NSS; val = xc[s * 32 + (c - 6)]; }
        }
        A1[r][c] = f2bf(val);
    }
    if (tid < 64) {
        int r = tid, g = row0 + r;
        float P = 0, E = 0, T1 = 0, T2 = 0;
        if (g < NROWS) { P = x[g * 6]; E = x[g * 6 + 1]; T1 = x[g * 6 + 2]; T2 = x[g * 6 + 3]; }
        float den = T2 - T1;
        float dg = (den == 0.0f) ? 1.0f : den;
        float ratio = fminf(fmaxf((T1 + T2) / dg, -1.0f), 1.0f);
        float vf = acosf(ratio) * (1.0f / 3.1415f);
        vf = (T1 >= 0.0f) ? 0.0f : ((T2 <= 0.0f) ? 1.0f : vf);
        pfE[r] = make_float2(P * (1.0f - vf), 2.0f * E);
        if (g < NROWS) {
            int tg = g / NSS, sg = g - tg * NSS;
            PTt[(size_t)sg * TPAD2 + tg] = make_float4(P * vf, T1, T2, vf);
        }
    }
    __syncthreads();

    int lane = tid & 63, wv = tid >> 6;
    int r16 = lane & 15;
    int kg = (lane >> 4) * 8;     // k offset within 32-chunk
    int rq = (lane >> 4) * 4;     // row offset of C frag

    // ---- layer 1: [64 x 64(Kpad)] @ [256 x 64]^T -> hidden (bf16) ----
    {
        int mt = wv & 3, nb = (wv >> 2) * 8;
        f32x4 acc[8];
#pragma unroll
        for (int i = 0; i < 8; ++i) acc[i] = (f32x4){0.f, 0.f, 0.f, 0.f};
#pragma unroll
        for (int ks = 0; ks < 2; ++ks) {
            bf16x8 a = *(const bf16x8*)&A1[mt * 16 + r16][ks * 32 + kg];
#pragma unroll
            for (int i = 0; i < 8; ++i) {
                bf16x8 b = *(const bf16x8*)(w1s + ((size_t)(((nb + i) * 2 + ks) * 64 + lane) << 3));
                acc[i] = __builtin_amdgcn_mfma_f32_16x16x32_bf16(a, b, acc[i], 0, 0, 0);
            }
        }
#pragma unroll
        for (int i = 0; i < 8; ++i) {
            int col = (nb + i) * 16 + r16;
            float bias = b1[col];
#pragma unroll
            for (int j = 0; j < 4; ++j) {
                int row = mt * 16 + rq + j;
                hb[row][col] = f2bf(tanhfast(acc[i][j] + bias));
            }
        }
    }
    __syncthreads();

    // ---- layer 2: [64 x 256] @ [384 x 256]^T, wave w -> col tiles {w, w+8, w+16} ----
    {
        int t0 = wv, t1 = wv + 8, t2 = wv + 16;
        f32x4 acc[4][3];
#pragma unroll
        for (int m = 0; m < 4; ++m)
#pragma unroll
            for (int c = 0; c < 3; ++c) acc[m][c] = (f32x4){0.f, 0.f, 0.f, 0.f};
#pragma unroll
        for (int ks = 0; ks < 8; ++ks) {
            bf16x8 b0 = *(const bf16x8*)(w2s + ((size_t)((t0 * 8 + ks) * 64 + lane) << 3));
            bf16x8 b1v = *(const bf16x8*)(w2s + ((size_t)((t1 * 8 + ks) * 64 + lane) << 3));
            bf16x8 b2v = *(const bf16x8*)(w2s + ((size_t)((t2 * 8 + ks) * 64 + lane) << 3));
#pragma unroll
            for (int m = 0; m < 4; ++m) {
                bf16x8 a = *(const bf16x8*)&hb[m * 16 + r16][ks * 32 + kg];
                acc[m][0] = __builtin_amdgcn_mfma_f32_16x16x32_bf16(a, b0, acc[m][0], 0, 0, 0);
                acc[m][1] = __builtin_amdgcn_mfma_f32_16x16x32_bf16(a, b1v, acc[m][1], 0, 0, 0);
                acc[m][2] = __builtin_amdgcn_mfma_f32_16x16x32_bf16(a, b2v, acc[m][2], 0, 0, 0);
            }
        }
        int hcol = wv * 16 + r16;     // h in [0,128)
        float bias0 = b2[hcol], bias1 = b2[128 + hcol], bias2 = b2[256 + hcol];
#pragma unroll
        for (int m = 0; m < 4; ++m) {
            float2 pf[4];
#pragma unroll
            for (int j = 0; j < 4; ++j) pf[j] = pfE[m * 16 + rq + j];
#pragma unroll
            for (int j = 0; j < 4; ++j) {
                int r = m * 16 + rq + j;
                int g = row0 + r;
                if (g < NROWS) {
                    float vi = fminf(fmaxf((acc[m][0][j] + bias0) * (1.0f / 3.0f) + 0.5f, 0.0f), 1.0f);
                    float pl = pf[j].x * vi;
                    float ev = pf[j].y * fmaxf(acc[m][1][j] + bias1, 0.0f);
                    float vmv = __expf(acc[m][2][j] + bias2);
                    unsigned pk = (unsigned)f2bf(pl - ev) | ((unsigned)f2bf(vmv) << 16);
                    int tg = g / NSS, sg = g - tg * NSS;
                    NVu[((size_t)sg * TPAD2 + tg) * 128 + hcol] = pk;
                }
            }
        }
    }
}

// ---------------- K3: role-split scan; ping-pong register prefetch ----------------
template<int ISC>
__device__ __forceinline__ void scan_loop(
    int lane, int s, int half,
    float kp, float ks, float kg, float gp, float gpc, float gL, float kpgl, float qb,
    float r0, float r1, float r2, float r3, float r4, float r5, float r6, float r7,
    float cpw0, float cpw1, float cpb, float csw0, float csw1, float csb,
    float cgw0, float cgw1, float cgb,
    const unsigned* __restrict__ nvsite, const float4* ptlds, float (*red)[68],
    float* __restrict__ outp)
{
    float Sf = 0.0f, Ss = 0.0f, Sg = 0.0f;
    float a0 = 0, a1 = 0, a2 = 0, a3 = 0, a4 = 0, a5 = 0, a6 = 0, a7 = 0;
    unsigned A[16], B[16];
    float4 pt[4];
#pragma unroll
    for (int i = 0; i < 16; ++i) A[i] = nvsite[(size_t)i * 128];
#pragma unroll
    for (int i = 0; i < 4; ++i) pt[i] = ptlds[i];

    auto STEP = [&](int t, int uu, unsigned nvu, unsigned& pref) {
        pref = nvsite[(size_t)(t + 16) * 128];     // 16-deep prefetch, disjoint buffer
        float net = __builtin_bit_cast(float, nvu << 16);
        float vm  = __builtin_bit_cast(float, nvu & 0xFFFF0000u);
        int ps = uu & 3;
        float psv = pt[ps].x, T1 = pt[ps].y, T2 = pt[ps].z;
        pt[ps] = ptlds[t + 4];
        float t1v = Sf + psv;
        float qf = fminf(t1v, vm);
        Sf = fmaxf(t1v - vm, 0.0f);
        float H = fmaxf(Ss + qf + net, 0.0f);
        float qp = fmaxf(kp * H - kpgl, 0.0f);
        float qs = ks * fminf(H, gL);
        Ss = H - qp - qs;
        float qso = qs * gpc;
        float qsg = qs * gp;
        float tg2 = Sg + qsg;
        float qg = kg * tg2 + qb;
        Sg = tg2 - qg;
        float val;
        if (ISC) {
            float cp = exp2f(cpw0 * T1 + cpw1 * T2 + cpb);
            float cs = exp2f(csw0 * T1 + csw1 * T2 + csb);
            float cg = exp2f(cgw0 * T1 + cgw1 * T2 + cgb);
            val = qp * cp + qso * cs + qg * cg;
        } else {
            val = qp + qso + qg;
        }
        a0 += val * r0; a1 += val * r1; a2 += val * r2; a3 += val * r3;
        a4 += val * r4; a5 += val * r5; a6 += val * r6; a7 += val * r7;
        red[uu & 15][lane] = a0;
        a0 = a1; a1 = a2; a2 = a3; a3 = a4; a4 = a5; a5 = a6; a6 = a7; a7 = 0.0f;
    };

    auto RED = [&](int base) {
        int v = lane >> 2, sub = lane & 3;    // v = step row 0..15
        const float4* rp4 = (const float4*)&red[v][0];
        float4 x0 = rp4[sub * 4 + 0];
        float4 x1 = rp4[sub * 4 + 1];
        float4 x2 = rp4[sub * 4 + 2];
        float4 x3 = rp4[sub * 4 + 3];
        float sA = (x0.x + x0.y) + (x0.z + x0.w);
        float sB = (x1.x + x1.y) + (x1.z + x1.w);
        float sC = (x2.x + x2.y) + (x2.z + x2.w);
        float sD = (x3.x + x3.y) + (x3.z + x3.w);
        float sm = (sA + sB) + (sC + sD);
        sm += __shfl_xor(sm, 1);
        sm += __shfl_xor(sm, 2);
        int tt = base + v;
        if (sub == 0 && tt < NTT)
            outp[((size_t)tt * NSS + s) * 2 + half] = sm;
    };

    for (int tb = 0; tb < 384; tb += 32) {
#pragma unroll
        for (int u = 0; u < 16; ++u) STEP(tb + u, u, A[u], B[u]);
        RED(tb);
#pragma unroll
        for (int u = 0; u < 16; ++u) STEP(tb + 16 + u, u + 16, B[u], A[u]);
        RED(tb + 16);
    }
}

__global__ __launch_bounds__(64, 2) void k_scan(
    const float* __restrict__ wsite, const float* __restrict__ rsite,
    const float* __restrict__ gaw,
    const float* __restrict__ ctp8, const float* __restrict__ ctpb,
    const float4* __restrict__ PTt, const unsigned* __restrict__ NVu,
    float* __restrict__ pQ, float* __restrict__ pC)
{
    __shared__ float4 ptlds[TPAD2];                // 6656 B
    __shared__ __align__(16) float red[16][68];    // 4352 B
    int lane = threadIdx.x;
    int b = blockIdx.x;
    // XCD-grouped: all 4 (half,role) blocks of a site -> same XCD (b mod 8 equal)
    int s = (b >> 5) * 8 + (b & 7);
    int hr = (b >> 3) & 3;
    int half = hr >> 1, role = hr & 1;
    if (s >= NSS) return;
    int h = half * 64 + lane;

    // one-time PT stage from [s][t] layout (coalesced); single wave -> no barrier
    for (int t = lane; t < TPAD2; t += 64) ptlds[t] = PTt[(size_t)s * TPAD2 + t];

    const float* wrow = wsite + s * 896;
    float kp = sigf(wrow[0 * 128 + h]);
    float ks = sigf(wrow[1 * 128 + h]);
    float kg = sigf(wrow[2 * 128 + h]);
    float gp = sigf(wrow[3 * 128 + h]);
    float gpc = 1.0f - gp;
    float gL = __expf(wrow[4 * 128 + h]) * 2.0f;
    float kpgl = kp * gL;
    float qb = fmaxf(wrow[5 * 128 + h], 0.0f);
    float ga = gaw[s * 128 + h];
    float4 rrA = *(const float4*)(rsite + s * 1024 + h * 8);
    float4 rrB = *(const float4*)(rsite + s * 1024 + h * 8 + 4);
    float r0 = fmaxf(rrA.x, 0.0f) * ga;
    float r1 = fmaxf(rrA.y, 0.0f) * ga;
    float r2 = fmaxf(rrA.z, 0.0f) * ga;
    float r3 = fmaxf(rrA.w, 0.0f) * ga;
    float r4 = fmaxf(rrB.x, 0.0f) * ga;
    float r5 = fmaxf(rrB.y, 0.0f) * ga;
    float r6 = fmaxf(rrB.z, 0.0f) * ga;
    float r7 = fmaxf(rrB.w, 0.0f) * ga;

    const unsigned* nvsite = NVu + (size_t)s * TPAD2 * 128 + h;

    if (role == 0) {
        scan_loop<0>(lane, s, half, kp, ks, kg, gp, gpc, gL, kpgl, qb,
                     r0, r1, r2, r3, r4, r5, r6, r7,
                     0.f, 0.f, 0.f, 0.f, 0.f, 0.f, 0.f, 0.f, 0.f,
                     nvsite, ptlds, red, pQ);
    } else {
        const float4* cp4 = (const float4*)(ctp8 + ((size_t)s * 128 + h) * 8);
        float4 c0 = cp4[0], c1 = cp4[1];
        float cgb = ctpb[(size_t)s * 128 + h];
        scan_loop<1>(lane, s, half, kp, ks, kg, gp, gpc, gL, kpgl, qb,
                     r0, r1, r2, r3, r4, r5, r6, r7,
                     c0.x, c0.y, c0.z, c0.w, c1.x, c1.y, c1.z, c1.w, cgb,
                     nvsite, ptlds, red, pC);
    }
}

// ---------------- K4: combine halves, divide ----------------
__global__ __launch_bounds__(256) void k_final(const float* __restrict__ pQ,
                                               const float* __restrict__ pC,
                                               float* __restrict__ out)
{
    int i = blockIdx.x * 256 + threadIdx.x;
    if (i < NROWS) {
        float q = pQ[i * 2] + pQ[i * 2 + 1];
        float c = pC[i * 2] + pC[i * 2 + 1];
        out[i] = q;
        out[NROWS + i] = c / q;
    }
}

extern "C" void kernel_launch(void* const* d_in, const int* in_sizes, int n_in,
                              void* d_out, int out_size, void* d_ws, size_t ws_size,
                              hipStream_t stream)
{
    const float* x      = (const float*)d_in[0];
    const float* xc     = (const float*)d_in[1];
    const float* fcR_w1 = (const float*)d_in[2];
    const float* fcR_b1 = (const float*)d_in[3];
    const float* fcR_w2 = (const float*)d_in[4];
    const float* fcR_b2 = (const float*)d_in[5];
    const float* fcW_w1 = (const float*)d_in[6];
    const float* fcW_b1 = (const float*)d_in[7];
    const float* fcW_w2 = (const float*)d_in[8];
    const float* fcW_b2 = (const float*)d_in[9];
    const float* fcT_w1 = (const float*)d_in[10];
    const float* fcT_b1 = (const float*)d_in[11];
    const float* fcT_w2 = (const float*)d_in[12];
    const float* fcT_b2 = (const float*)d_in[13];
    const float* fcCT_w = (const float*)d_in[14];
    const float* fcCT_b = (const float*)d_in[15];
    float* out = (float*)d_out;

    float* ws = (float*)d_ws;
    size_t o_w    = 0;                                     // 300*896
    size_t o_r    = o_w  + 300 * 896;                      // 300*1024
    size_t o_ga   = o_r  + 300 * 1024;                     // 300*128
    size_t o_PT   = o_ga + 300 * 128;                      // NSS*TPAD2 float4
    size_t o_NV   = o_PT + (size_t)TPAD2 * NSS * 4;        // NSS*TPAD2*128 u32
    size_t o_pQ   = o_NV + (size_t)TPAD2 * NSS * 128;      // NROWS*2
    size_t o_pC   = o_pQ + (size_t)NROWS * 2;              // NROWS*2
    size_t o_w1bf = o_pC + (size_t)NROWS * 2;
    size_t o_w2bf = o_w1bf + 8192;
    size_t o_ctp  = o_w2bf + 49152;                        // 300*128*8
    size_t o_ctpb = o_ctp + (size_t)300 * 128 * 8;         // 300*128

    float* wsite = ws + o_w;
    float* rsite = ws + o_r;
    float* gaw   = ws + o_ga;
    float4* PTt  = (float4*)(ws + o_PT);
    unsigned* NVu = (unsigned*)(ws + o_NV);
    float* pQ    = ws + o_pQ;
    float* pC    = ws + o_pC;
    unsigned short* w1s = (unsigned short*)(ws + o_w1bf);
    unsigned short* w2s = (unsigned short*)(ws + o_w2bf);
    float* ctp8  = ws + o_ctp;
    float* ctpb  = ws + o_ctpb;

    k_prep<<<56, 256, 0, stream>>>(fcT_w1, fcT_w2, w1s, w2s);
    k_site<<<dim3(30, 8), 256, 0, stream>>>(xc, fcW_w1, fcW_b1, fcW_w2, fcW_b2,
                                            fcR_w1, fcR_b1, fcR_w2, fcR_b2, wsite, rsite);
    k_softmax_ga<<<300, 128, 0, stream>>>(wsite, gaw);
    k_ct<<<300, 128, 0, stream>>>(xc, fcCT_w, fcCT_b, ctp8, ctpb);
    int nblk2 = (NROWS + 63) / 64;   // 1711
    k_fcT<<<nblk2, 512, 0, stream>>>(x, xc, w1s, fcT_b1, w2s, fcT_b2, PTt, NVu);
    // 300 sites x {half,role}: grouped so one site's 4 blocks share an XCD; 38*32=1216
    k_scan<<<1216, 64, 0, stream>>>(wsite, rsite, gaw, ctp8, ctpb,
                                    PTt, NVu, pQ, pC);
    k_final<<<(NROWS + 255) / 256, 256, 0, stream>>>(pQ, pC, out);
}